// Round 1
// baseline (8497.103 us; speedup 1.0000x reference)
//
#include <hip/hip_runtime.h>

#define N_NODES 100000
#define N_EDGES 1600000
#define N_GRAPHS 64
#define HID 256
#define PROJ 128
#define NLAYERS 4

// ---------------------------------------------------------------- counts ----
__global__ void count_kernel(const int* __restrict__ dst, float* __restrict__ cnt) {
  int e = blockIdx.x * blockDim.x + threadIdx.x;
  if (e < N_EDGES) atomicAdd(&cnt[dst[e]], 1.0f);
}

__global__ void inv_kernel(float* __restrict__ cnt) {
  int n = blockIdx.x * blockDim.x + threadIdx.x;
  if (n < N_NODES) cnt[n] = 1.0f / fmaxf(cnt[n], 1.0f);
}

// ------------------------------------------------------------- scatter ------
#define EDGES_PER_BLOCK 8
__global__ __launch_bounds__(256) void scatter_kernel(
    const float* __restrict__ h, const int* __restrict__ src,
    const int* __restrict__ dst, float* __restrict__ aggr) {
  int f = threadIdx.x;
  int e0 = blockIdx.x * EDGES_PER_BLOCK;
  int e1 = min(e0 + EDGES_PER_BLOCK, N_EDGES);
  for (int e = e0; e < e1; e++) {
    int s = src[e], d = dst[e];
    atomicAdd(&aggr[(size_t)d * HID + f], h[(size_t)s * HID + f]);
  }
}

// ---------------------------------------------------------------- GEMM ------
// out[m][j] = sum_k cat(aggr*inv, h)[m][k] * cat(Wl;Wr)[k][j] + bias[j]
__global__ __launch_bounds__(256) void gemm_kernel(
    const float* __restrict__ h, const float* __restrict__ aggr,
    const float* __restrict__ inv_cnt,
    const float* __restrict__ Wl, const float* __restrict__ Wr,
    const float* __restrict__ bias, float* __restrict__ outp) {
  __shared__ float As[16][65];
  __shared__ float Ws[16][64];
  int tid = threadIdx.x;
  int tx = tid & 15, ty = tid >> 4;
  int m0 = blockIdx.x * 64;
  int n0 = blockIdx.y * 64;
  float acc[4][4] = {};
  for (int k0 = 0; k0 < 2 * HID; k0 += 16) {
#pragma unroll
    for (int i = 0; i < 4; i++) {
      int idx = tid + i * 256;
      int kk = idx & 15, mm = idx >> 4;
      int gm = m0 + mm, gk = k0 + kk;
      float v = 0.f;
      if (gm < N_NODES) {
        v = (gk < HID) ? aggr[(size_t)gm * HID + gk] * inv_cnt[gm]
                       : h[(size_t)gm * HID + (gk - HID)];
      }
      As[kk][mm] = v;
    }
#pragma unroll
    for (int i = 0; i < 4; i++) {
      int idx = tid + i * 256;
      int jj = idx & 63, kk = idx >> 6;
      int gk = k0 + kk;
      Ws[kk][jj] = (gk < HID) ? Wl[(size_t)gk * HID + n0 + jj]
                              : Wr[(size_t)(gk - HID) * HID + n0 + jj];
    }
    __syncthreads();
#pragma unroll
    for (int k = 0; k < 16; k++) {
      float a[4], b[4];
#pragma unroll
      for (int i = 0; i < 4; i++) a[i] = As[k][ty * 4 + i];
#pragma unroll
      for (int j = 0; j < 4; j++) b[j] = Ws[k][tx * 4 + j];
#pragma unroll
      for (int i = 0; i < 4; i++)
#pragma unroll
        for (int j = 0; j < 4; j++) acc[i][j] = fmaf(a[i], b[j], acc[i][j]);
    }
    __syncthreads();
  }
#pragma unroll
  for (int i = 0; i < 4; i++) {
    int gm = m0 + ty * 4 + i;
    if (gm >= N_NODES) continue;
#pragma unroll
    for (int j = 0; j < 4; j++) {
      int gj = n0 + tx * 4 + j;
      outp[(size_t)gm * HID + gj] = acc[i][j] + bias[gj];
    }
  }
}

// ------------------------------------------------------------ batchnorm -----
__global__ __launch_bounds__(256) void bn_reduce(const float* __restrict__ h,
                                                 float* __restrict__ sums) {
  int f = threadIdx.x;
  int r0 = blockIdx.x * 256;
  int r1 = min(r0 + 256, N_NODES);
  float s = 0.f, s2 = 0.f;
  for (int r = r0; r < r1; r++) {
    float v = h[(size_t)r * HID + f];
    s += v;
    s2 += v * v;
  }
  atomicAdd(&sums[f], s);
  atomicAdd(&sums[HID + f], s2);
}

__global__ void bn_finalize(const float* __restrict__ sums,
                            const float* __restrict__ gamma,
                            const float* __restrict__ beta,
                            float* __restrict__ ss) {
  int f = threadIdx.x;
  const float invN = 1.0f / (float)N_NODES;
  float mu = sums[f] * invN;
  float ex2 = sums[HID + f] * invN;
  float var = fmaxf(ex2 - mu * mu, 0.f);
  float sc = gamma[f] * rsqrtf(var + 1e-5f);
  ss[f] = sc;
  ss[HID + f] = beta[f] - mu * sc;
}

__global__ __launch_bounds__(256) void bn_apply(float4* __restrict__ h,
                                                const float* __restrict__ ss) {
  // gridDim.x*blockDim.x must be a multiple of 64 so each thread's column is fixed
  long long i0 = (long long)blockIdx.x * blockDim.x + threadIdx.x;
  int f = (int)((i0 & 63) << 2);
  float sc0 = ss[f], sc1 = ss[f + 1], sc2 = ss[f + 2], sc3 = ss[f + 3];
  float sh0 = ss[HID + f], sh1 = ss[HID + f + 1], sh2 = ss[HID + f + 2], sh3 = ss[HID + f + 3];
  const long long total = (long long)N_NODES * (HID / 4);
  const long long step = (long long)gridDim.x * blockDim.x;
  for (long long i = i0; i < total; i += step) {
    float4 v = h[i];
    v.x = fmaxf(fmaf(v.x, sc0, sh0), 0.f);
    v.y = fmaxf(fmaf(v.y, sc1, sh1), 0.f);
    v.z = fmaxf(fmaf(v.z, sc2, sh2), 0.f);
    v.w = fmaxf(fmaf(v.w, sc3, sh3), 0.f);
    h[i] = v;
  }
}

// ----------------------------------------------------------------- pool -----
#define ROWS_PER_BLOCK 512
__global__ __launch_bounds__(256) void pool_kernel(const float* __restrict__ h,
                                                   const int* __restrict__ batch,
                                                   float* __restrict__ gacc,
                                                   float* __restrict__ gcnt) {
  int f = threadIdx.x;
  int r0 = blockIdx.x * ROWS_PER_BLOCK;
  if (r0 >= N_NODES) return;
  int r1 = min(r0 + ROWS_PER_BLOCK, N_NODES);
  int cur = batch[r0];
  float acc = 0.f, count = 0.f;
  for (int r = r0; r < r1; r++) {
    int b = batch[r];
    if (b != cur) {
      atomicAdd(&gacc[(size_t)cur * HID + f], acc);
      if (f == 0) atomicAdd(&gcnt[cur], count);
      acc = 0.f;
      count = 0.f;
      cur = b;
    }
    acc += h[(size_t)r * HID + f];
    count += 1.f;
  }
  atomicAdd(&gacc[(size_t)cur * HID + f], acc);
  if (f == 0) atomicAdd(&gcnt[cur], count);
}

// ------------------------------------------------------------------ MLP -----
__global__ __launch_bounds__(256) void mlp_kernel(
    const float* __restrict__ gacc, const float* __restrict__ gcnt,
    const float* __restrict__ W1, const float* __restrict__ b1,
    const float* __restrict__ W2, const float* __restrict__ b2,
    float* __restrict__ out) {
  __shared__ float gs[HID];
  __shared__ float ts[HID];
  __shared__ float red[PROJ];
  int g = blockIdx.x;
  int t = threadIdx.x;
  float inv = 1.0f / fmaxf(gcnt[g], 1.0f);
  gs[t] = gacc[(size_t)g * HID + t] * inv;
  __syncthreads();
  float s = b1[t];
  for (int k = 0; k < HID; k++) s = fmaf(gs[k], W1[(size_t)k * HID + t], s);
  ts[t] = fmaxf(s, 0.f);
  __syncthreads();
  float z = 0.f;
  if (t < PROJ) {
    z = b2[t];
    for (int k = 0; k < HID; k++) z = fmaf(ts[k], W2[(size_t)k * PROJ + t], z);
    red[t] = z * z;
  }
  __syncthreads();
  for (int off = PROJ / 2; off > 0; off >>= 1) {
    if (t < off) red[t] += red[t + off];
    __syncthreads();
  }
  float norm = fmaxf(sqrtf(red[0]), 1e-12f);
  if (t < PROJ) out[(size_t)g * PROJ + t] = z / norm;
}

// --------------------------------------------------------------- launch -----
extern "C" void kernel_launch(void* const* d_in, const int* in_sizes, int n_in,
                              void* d_out, int out_size, void* d_ws, size_t ws_size,
                              hipStream_t stream) {
  const float* x = (const float*)d_in[0];
  const int* ei = (const int*)d_in[1];
  const int* src = ei;
  const int* dst = ei + N_EDGES;
  const int* batch = (const int*)d_in[2];
  const float* Wl = (const float*)d_in[3];
  const float* bl = (const float*)d_in[4];
  const float* Wr = (const float*)d_in[5];
  const float* gamma = (const float*)d_in[6];
  const float* beta = (const float*)d_in[7];
  const float* W1 = (const float*)d_in[8];
  const float* b1 = (const float*)d_in[9];
  const float* W2 = (const float*)d_in[10];
  const float* b2 = (const float*)d_in[11];
  float* out = (float*)d_out;

  char* ws = (char*)d_ws;
  const size_t NB = (size_t)N_NODES * HID * sizeof(float);  // 102.4 MB
  float* B1 = (float*)ws;
  float* B2 = (float*)(ws + NB);
  float* aggr = (float*)(ws + 2 * NB);
  float* cnt = (float*)(ws + 3 * NB);                 // 100000 floats
  float* sums = (float*)(ws + 3 * NB + 524288);       // 512 floats
  float* ss = sums + 512;                              // 512 floats
  float* gacc = ss + 512;                              // 64*256 floats
  float* gcnt = gacc + N_GRAPHS * HID;                 // 64 floats

  // in-degree counts (dst-only, same for all layers)
  hipMemsetAsync(cnt, 0, (size_t)N_NODES * sizeof(float), stream);
  count_kernel<<<(N_EDGES + 255) / 256, 256, 0, stream>>>(dst, cnt);
  inv_kernel<<<(N_NODES + 255) / 256, 256, 0, stream>>>(cnt);

  const float* h = x;
  float* pp[2] = {B1, B2};
  for (int l = 0; l < NLAYERS; l++) {
    float* hout = pp[l & 1];
    hipMemsetAsync(aggr, 0, NB, stream);
    scatter_kernel<<<N_EDGES / EDGES_PER_BLOCK, 256, 0, stream>>>(h, src, dst, aggr);
    gemm_kernel<<<dim3((N_NODES + 63) / 64, HID / 64), 256, 0, stream>>>(
        h, aggr, cnt, Wl + (size_t)l * HID * HID, Wr + (size_t)l * HID * HID,
        bl + (size_t)l * HID, hout);
    hipMemsetAsync(sums, 0, 512 * sizeof(float), stream);
    bn_reduce<<<(N_NODES + 255) / 256, 256, 0, stream>>>(hout, sums);
    bn_finalize<<<1, 256, 0, stream>>>(sums, gamma + (size_t)l * HID,
                                       beta + (size_t)l * HID, ss);
    bn_apply<<<2048, 256, 0, stream>>>((float4*)hout, ss);
    h = hout;
  }

  hipMemsetAsync(gacc, 0, (size_t)(N_GRAPHS * HID + N_GRAPHS) * sizeof(float), stream);
  pool_kernel<<<(N_NODES + ROWS_PER_BLOCK - 1) / ROWS_PER_BLOCK, 256, 0, stream>>>(
      h, batch, gacc, gcnt);
  mlp_kernel<<<N_GRAPHS, 256, 0, stream>>>(gacc, gcnt, W1, b1, W2, b2, out);
}

// Round 2
// 4334.778 us; speedup vs baseline: 1.9602x; 1.9602x over previous
//
#include <hip/hip_runtime.h>

#define N_NODES 100000
#define N_EDGES 1600000
#define N_GRAPHS 64
#define HID 256
#define PROJ 128
#define NLAYERS 4

// ---------------------------------------------------------------- counts ----
__global__ void count_kernel(const int* __restrict__ dst, int* __restrict__ cnt) {
  int e = blockIdx.x * blockDim.x + threadIdx.x;
  if (e < N_EDGES) atomicAdd(&cnt[dst[e]], 1);
}

__global__ void inv_kernel(const int* __restrict__ cnt, float* __restrict__ inv) {
  int n = blockIdx.x * blockDim.x + threadIdx.x;
  if (n < N_NODES) inv[n] = 1.0f / fmaxf((float)cnt[n], 1.0f);
}

// single-block exclusive scan of counts -> row_ptr
__global__ __launch_bounds__(256) void scan_kernel(const int* __restrict__ cnt,
                                                   int* __restrict__ row_ptr) {
  __shared__ int tile[256];
  __shared__ int carry_s;
  int t = threadIdx.x;
  if (t == 0) carry_s = 0;
  __syncthreads();
  for (int base = 0; base < N_NODES; base += 256) {
    int i = base + t;
    int v = (i < N_NODES) ? cnt[i] : 0;
    tile[t] = v;
    __syncthreads();
#pragma unroll
    for (int off = 1; off < 256; off <<= 1) {
      int add = (t >= off) ? tile[t - off] : 0;
      __syncthreads();
      tile[t] += add;
      __syncthreads();
    }
    int incl = tile[t];
    int c = carry_s;
    if (i < N_NODES) row_ptr[i] = c + incl - v;
    __syncthreads();
    if (t == 255) carry_s = c + incl;
    __syncthreads();
  }
  if (t == 0) row_ptr[N_NODES] = N_EDGES;
}

__global__ void fill_kernel(const int* __restrict__ src, const int* __restrict__ dst,
                            const int* __restrict__ row_ptr, int* __restrict__ fill,
                            int* __restrict__ col) {
  int e = blockIdx.x * blockDim.x + threadIdx.x;
  if (e < N_EDGES) {
    int d = dst[e];
    int pos = row_ptr[d] + atomicAdd(&fill[d], 1);
    col[pos] = src[e];
  }
}

// ----------------------------------------------------------- aggregation ----
// one wave per node; lane holds float4 at feature offset lane*4
__global__ __launch_bounds__(256) void aggregate_kernel(
    const float* __restrict__ h, const int* __restrict__ row_ptr,
    const int* __restrict__ col, const float* __restrict__ inv_cnt,
    float* __restrict__ aggr) {
  int node = blockIdx.x * 4 + (threadIdx.x >> 6);
  if (node >= N_NODES) return;
  int lane = threadIdx.x & 63;
  int r0 = row_ptr[node];
  int r1 = row_ptr[node + 1];
  float4 a0 = {0.f, 0.f, 0.f, 0.f};
  float4 a1 = {0.f, 0.f, 0.f, 0.f};
  int r = r0;
  for (; r + 2 <= r1; r += 2) {
    int s0 = col[r], s1 = col[r + 1];
    float4 v0 = ((const float4*)(h + (size_t)s0 * HID))[lane];
    float4 v1 = ((const float4*)(h + (size_t)s1 * HID))[lane];
    a0.x += v0.x; a0.y += v0.y; a0.z += v0.z; a0.w += v0.w;
    a1.x += v1.x; a1.y += v1.y; a1.z += v1.z; a1.w += v1.w;
  }
  if (r < r1) {
    int s0 = col[r];
    float4 v0 = ((const float4*)(h + (size_t)s0 * HID))[lane];
    a0.x += v0.x; a0.y += v0.y; a0.z += v0.z; a0.w += v0.w;
  }
  float inv = inv_cnt[node];
  float4 o;
  o.x = (a0.x + a1.x) * inv;
  o.y = (a0.y + a1.y) * inv;
  o.z = (a0.z + a1.z) * inv;
  o.w = (a0.w + a1.w) * inv;
  ((float4*)(aggr + (size_t)node * HID))[lane] = o;
}

// ---------------------------------------------------------------- GEMM ------
// out[m][j] = sum_k cat(aggr, h)[m][k] * cat(Wl;Wr)[k][j] + bias[j]
__global__ __launch_bounds__(256) void gemm_kernel(
    const float* __restrict__ h, const float* __restrict__ aggr,
    const float* __restrict__ Wl, const float* __restrict__ Wr,
    const float* __restrict__ bias, float* __restrict__ outp) {
  __shared__ float As[16][65];
  __shared__ float Ws[16][64];
  int tid = threadIdx.x;
  int tx = tid & 15, ty = tid >> 4;
  int m0 = blockIdx.x * 64;
  int n0 = blockIdx.y * 64;
  float acc[4][4] = {};
  for (int k0 = 0; k0 < 2 * HID; k0 += 16) {
#pragma unroll
    for (int i = 0; i < 4; i++) {
      int idx = tid + i * 256;
      int kk = idx & 15, mm = idx >> 4;
      int gm = m0 + mm, gk = k0 + kk;
      float v = 0.f;
      if (gm < N_NODES) {
        v = (gk < HID) ? aggr[(size_t)gm * HID + gk]
                       : h[(size_t)gm * HID + (gk - HID)];
      }
      As[kk][mm] = v;
    }
#pragma unroll
    for (int i = 0; i < 4; i++) {
      int idx = tid + i * 256;
      int jj = idx & 63, kk = idx >> 6;
      int gk = k0 + kk;
      Ws[kk][jj] = (gk < HID) ? Wl[(size_t)gk * HID + n0 + jj]
                              : Wr[(size_t)(gk - HID) * HID + n0 + jj];
    }
    __syncthreads();
#pragma unroll
    for (int k = 0; k < 16; k++) {
      float a[4], b[4];
#pragma unroll
      for (int i = 0; i < 4; i++) a[i] = As[k][ty * 4 + i];
#pragma unroll
      for (int j = 0; j < 4; j++) b[j] = Ws[k][tx * 4 + j];
#pragma unroll
      for (int i = 0; i < 4; i++)
#pragma unroll
        for (int j = 0; j < 4; j++) acc[i][j] = fmaf(a[i], b[j], acc[i][j]);
    }
    __syncthreads();
  }
#pragma unroll
  for (int i = 0; i < 4; i++) {
    int gm = m0 + ty * 4 + i;
    if (gm >= N_NODES) continue;
#pragma unroll
    for (int j = 0; j < 4; j++) {
      int gj = n0 + tx * 4 + j;
      outp[(size_t)gm * HID + gj] = acc[i][j] + bias[gj];
    }
  }
}

// ------------------------------------------------------------ batchnorm -----
__global__ __launch_bounds__(256) void bn_reduce(const float* __restrict__ h,
                                                 float* __restrict__ sums) {
  int f = threadIdx.x;
  int r0 = blockIdx.x * 256;
  int r1 = min(r0 + 256, N_NODES);
  float s = 0.f, s2 = 0.f;
  for (int r = r0; r < r1; r++) {
    float v = h[(size_t)r * HID + f];
    s += v;
    s2 += v * v;
  }
  atomicAdd(&sums[f], s);
  atomicAdd(&sums[HID + f], s2);
}

__global__ void bn_finalize(const float* __restrict__ sums,
                            const float* __restrict__ gamma,
                            const float* __restrict__ beta,
                            float* __restrict__ ss) {
  int f = threadIdx.x;
  const float invN = 1.0f / (float)N_NODES;
  float mu = sums[f] * invN;
  float ex2 = sums[HID + f] * invN;
  float var = fmaxf(ex2 - mu * mu, 0.f);
  float sc = gamma[f] * rsqrtf(var + 1e-5f);
  ss[f] = sc;
  ss[HID + f] = beta[f] - mu * sc;
}

__global__ __launch_bounds__(256) void bn_apply(float4* __restrict__ h,
                                                const float* __restrict__ ss) {
  long long i0 = (long long)blockIdx.x * blockDim.x + threadIdx.x;
  int f = (int)((i0 & 63) << 2);
  float sc0 = ss[f], sc1 = ss[f + 1], sc2 = ss[f + 2], sc3 = ss[f + 3];
  float sh0 = ss[HID + f], sh1 = ss[HID + f + 1], sh2 = ss[HID + f + 2], sh3 = ss[HID + f + 3];
  const long long total = (long long)N_NODES * (HID / 4);
  const long long step = (long long)gridDim.x * blockDim.x;
  for (long long i = i0; i < total; i += step) {
    float4 v = h[i];
    v.x = fmaxf(fmaf(v.x, sc0, sh0), 0.f);
    v.y = fmaxf(fmaf(v.y, sc1, sh1), 0.f);
    v.z = fmaxf(fmaf(v.z, sc2, sh2), 0.f);
    v.w = fmaxf(fmaf(v.w, sc3, sh3), 0.f);
    h[i] = v;
  }
}

// ----------------------------------------------------------------- pool -----
#define ROWS_PER_BLOCK 512
__global__ __launch_bounds__(256) void pool_kernel(const float* __restrict__ h,
                                                   const int* __restrict__ batch,
                                                   float* __restrict__ gacc,
                                                   float* __restrict__ gcnt) {
  int f = threadIdx.x;
  int r0 = blockIdx.x * ROWS_PER_BLOCK;
  if (r0 >= N_NODES) return;
  int r1 = min(r0 + ROWS_PER_BLOCK, N_NODES);
  int cur = batch[r0];
  float acc = 0.f, count = 0.f;
  for (int r = r0; r < r1; r++) {
    int b = batch[r];
    if (b != cur) {
      atomicAdd(&gacc[(size_t)cur * HID + f], acc);
      if (f == 0) atomicAdd(&gcnt[cur], count);
      acc = 0.f;
      count = 0.f;
      cur = b;
    }
    acc += h[(size_t)r * HID + f];
    count += 1.f;
  }
  atomicAdd(&gacc[(size_t)cur * HID + f], acc);
  if (f == 0) atomicAdd(&gcnt[cur], count);
}

// ------------------------------------------------------------------ MLP -----
__global__ __launch_bounds__(256) void mlp_kernel(
    const float* __restrict__ gacc, const float* __restrict__ gcnt,
    const float* __restrict__ W1, const float* __restrict__ b1,
    const float* __restrict__ W2, const float* __restrict__ b2,
    float* __restrict__ out) {
  __shared__ float gs[HID];
  __shared__ float ts[HID];
  __shared__ float red[PROJ];
  int g = blockIdx.x;
  int t = threadIdx.x;
  float inv = 1.0f / fmaxf(gcnt[g], 1.0f);
  gs[t] = gacc[(size_t)g * HID + t] * inv;
  __syncthreads();
  float s = b1[t];
  for (int k = 0; k < HID; k++) s = fmaf(gs[k], W1[(size_t)k * HID + t], s);
  ts[t] = fmaxf(s, 0.f);
  __syncthreads();
  float z = 0.f;
  if (t < PROJ) {
    z = b2[t];
    for (int k = 0; k < HID; k++) z = fmaf(ts[k], W2[(size_t)k * PROJ + t], z);
    red[t] = z * z;
  }
  __syncthreads();
  for (int off = PROJ / 2; off > 0; off >>= 1) {
    if (t < off) red[t] += red[t + off];
    __syncthreads();
  }
  float norm = fmaxf(sqrtf(red[0]), 1e-12f);
  if (t < PROJ) out[(size_t)g * PROJ + t] = z / norm;
}

// --------------------------------------------------------------- launch -----
extern "C" void kernel_launch(void* const* d_in, const int* in_sizes, int n_in,
                              void* d_out, int out_size, void* d_ws, size_t ws_size,
                              hipStream_t stream) {
  const float* x = (const float*)d_in[0];
  const int* ei = (const int*)d_in[1];
  const int* src = ei;
  const int* dst = ei + N_EDGES;
  const int* batch = (const int*)d_in[2];
  const float* Wl = (const float*)d_in[3];
  const float* bl = (const float*)d_in[4];
  const float* Wr = (const float*)d_in[5];
  const float* gamma = (const float*)d_in[6];
  const float* beta = (const float*)d_in[7];
  const float* W1 = (const float*)d_in[8];
  const float* b1 = (const float*)d_in[9];
  const float* W2 = (const float*)d_in[10];
  const float* b2 = (const float*)d_in[11];
  float* out = (float*)d_out;

  char* p = (char*)d_ws;
  const size_t NB = (size_t)N_NODES * HID * sizeof(float);  // 102.4 MB
  float* B1 = (float*)p;            p += NB;
  float* B2 = (float*)p;            p += NB;
  float* aggr = (float*)p;          p += NB;
  int* col = (int*)p;               p += (size_t)N_EDGES * sizeof(int);   // 6.4 MB
  int* row_ptr = (int*)p;           p += ((N_NODES + 1) * sizeof(int) + 15) / 16 * 16;
  float* inv_cnt = (float*)p;       p += (size_t)N_NODES * sizeof(float);
  float* sums = (float*)p;          p += 512 * sizeof(float);
  float* ss = (float*)p;            p += 512 * sizeof(float);
  float* gacc = (float*)p;          p += (size_t)N_GRAPHS * HID * sizeof(float);
  float* gcnt = (float*)p;          p += N_GRAPHS * sizeof(float);

  // transient CSR-build arrays overlaid into B1 (B1 first written by layer-0 gemm)
  int* counts = (int*)B1;
  int* fill = counts + N_NODES;

  // ---- build CSR (once; edge_index is layer-invariant) ----
  hipMemsetAsync(counts, 0, 2 * (size_t)N_NODES * sizeof(int), stream);
  count_kernel<<<(N_EDGES + 255) / 256, 256, 0, stream>>>(dst, counts);
  inv_kernel<<<(N_NODES + 255) / 256, 256, 0, stream>>>(counts, inv_cnt);
  scan_kernel<<<1, 256, 0, stream>>>(counts, row_ptr);
  fill_kernel<<<(N_EDGES + 255) / 256, 256, 0, stream>>>(src, dst, row_ptr, fill, col);

  const float* h = x;
  float* pp[2] = {B1, B2};
  for (int l = 0; l < NLAYERS; l++) {
    float* hout = pp[l & 1];
    aggregate_kernel<<<(N_NODES + 3) / 4, 256, 0, stream>>>(h, row_ptr, col, inv_cnt, aggr);
    gemm_kernel<<<dim3((N_NODES + 63) / 64, HID / 64), 256, 0, stream>>>(
        h, aggr, Wl + (size_t)l * HID * HID, Wr + (size_t)l * HID * HID,
        bl + (size_t)l * HID, hout);
    hipMemsetAsync(sums, 0, 512 * sizeof(float), stream);
    bn_reduce<<<(N_NODES + 255) / 256, 256, 0, stream>>>(hout, sums);
    bn_finalize<<<1, 256, 0, stream>>>(sums, gamma + (size_t)l * HID,
                                       beta + (size_t)l * HID, ss);
    bn_apply<<<2048, 256, 0, stream>>>((float4*)hout, ss);
    h = hout;
  }

  hipMemsetAsync(gacc, 0, (size_t)(N_GRAPHS * HID + N_GRAPHS) * sizeof(float), stream);
  pool_kernel<<<(N_NODES + ROWS_PER_BLOCK - 1) / ROWS_PER_BLOCK, 256, 0, stream>>>(
      h, batch, gacc, gcnt);
  mlp_kernel<<<N_GRAPHS, 256, 0, stream>>>(gacc, gcnt, W1, b1, W2, b2, out);
}

// Round 3
// 1731.215 us; speedup vs baseline: 4.9082x; 2.5039x over previous
//
#include <hip/hip_runtime.h>

#define N_NODES 100000
#define M_PAD   100096   // 782 * 128
#define N_EDGES 1600000
#define N_GRAPHS 64
#define HID 256
#define PROJ 128
#define NLAYERS 4

typedef unsigned short u16;
typedef __attribute__((ext_vector_type(8))) short bf16x8;
typedef __attribute__((ext_vector_type(4))) float f32x4;

__device__ __forceinline__ float b2f(u16 u) {
  return __uint_as_float(((unsigned)u) << 16);
}
__device__ __forceinline__ u16 f2b(float f) {
  unsigned u = __float_as_uint(f);
  u = (u + 0x7FFF + ((u >> 16) & 1)) >> 16;  // round-to-nearest-even
  return (u16)u;
}
__device__ __forceinline__ void gload16(const void* g, void* l) {
  __builtin_amdgcn_global_load_lds((const __attribute__((address_space(1))) void*)g,
                                   (__attribute__((address_space(3))) void*)l, 16, 0, 0);
}

// ---------------------------------------------------------------- CSR -------
__global__ void count_kernel(const int* __restrict__ dst, int* __restrict__ cnt) {
  int e = blockIdx.x * blockDim.x + threadIdx.x;
  if (e < N_EDGES) atomicAdd(&cnt[dst[e]], 1);
}

__global__ void inv_kernel(const int* __restrict__ cnt, float* __restrict__ inv) {
  int n = blockIdx.x * blockDim.x + threadIdx.x;
  if (n < N_NODES) inv[n] = 1.0f / fmaxf((float)cnt[n], 1.0f);
}

__global__ __launch_bounds__(256) void scan_kernel(const int* __restrict__ cnt,
                                                   int* __restrict__ row_ptr) {
  __shared__ int tile[256];
  __shared__ int carry_s;
  int t = threadIdx.x;
  if (t == 0) carry_s = 0;
  __syncthreads();
  for (int base = 0; base < N_NODES; base += 256) {
    int i = base + t;
    int v = (i < N_NODES) ? cnt[i] : 0;
    tile[t] = v;
    __syncthreads();
#pragma unroll
    for (int off = 1; off < 256; off <<= 1) {
      int add = (t >= off) ? tile[t - off] : 0;
      __syncthreads();
      tile[t] += add;
      __syncthreads();
    }
    int incl = tile[t];
    int c = carry_s;
    if (i < N_NODES) row_ptr[i] = c + incl - v;
    __syncthreads();
    if (t == 255) carry_s = c + incl;
    __syncthreads();
  }
  if (t == 0) row_ptr[N_NODES] = N_EDGES;
}

__global__ void fill_kernel(const int* __restrict__ src, const int* __restrict__ dst,
                            const int* __restrict__ row_ptr, int* __restrict__ fill,
                            int* __restrict__ col) {
  int e = blockIdx.x * blockDim.x + threadIdx.x;
  if (e < N_EDGES) {
    int d = dst[e];
    int pos = row_ptr[d] + atomicAdd(&fill[d], 1);
    col[pos] = src[e];
  }
}

// ------------------------------------------------------------ converts ------
__global__ __launch_bounds__(256) void convert_x(const float4* __restrict__ x,
                                                 ushort4* __restrict__ hb) {
  int i = blockIdx.x * blockDim.x + threadIdx.x;  // exactly N_NODES*64 threads
  float4 v = x[i];
  ushort4 o;
  o.x = f2b(v.x); o.y = f2b(v.y); o.z = f2b(v.z); o.w = f2b(v.w);
  hb[i] = o;
}

// Wt[l][n][k] bf16, k<256 -> Wl[l][k][n], k>=256 -> Wr[l][k-256][n]
__global__ __launch_bounds__(256) void convert_w(const float* __restrict__ Wl,
                                                 const float* __restrict__ Wr,
                                                 u16* __restrict__ Wt) {
  int idx = blockIdx.x * blockDim.x + threadIdx.x;  // 4*256*512 threads
  int l = idx >> 17;
  int r = idx & ((1 << 17) - 1);
  int n = r >> 9;
  int k = r & 511;
  float v = (k < 256) ? Wl[(size_t)l * 65536 + k * 256 + n]
                      : Wr[(size_t)l * 65536 + (k - 256) * 256 + n];
  Wt[idx] = f2b(v);
}

// ----------------------------------------------------------- aggregation ----
// one wave per node; lane holds features [lane*4, lane*4+3]
__global__ __launch_bounds__(256) void aggregate_bf16(
    const u16* __restrict__ h, const int* __restrict__ row_ptr,
    const int* __restrict__ col, const float* __restrict__ inv_cnt,
    u16* __restrict__ aggr) {
  int node = blockIdx.x * 4 + (threadIdx.x >> 6);
  int lane = threadIdx.x & 63;
  int r0 = row_ptr[node], r1 = row_ptr[node + 1];
  float4 a0 = {0.f, 0.f, 0.f, 0.f}, a1 = a0, a2 = a0, a3 = a0;
  int r = r0;
  for (; r + 4 <= r1; r += 4) {
    int s0 = col[r], s1 = col[r + 1], s2 = col[r + 2], s3 = col[r + 3];
    ushort4 v0 = *((const ushort4*)(h + (size_t)s0 * HID) + lane);
    ushort4 v1 = *((const ushort4*)(h + (size_t)s1 * HID) + lane);
    ushort4 v2 = *((const ushort4*)(h + (size_t)s2 * HID) + lane);
    ushort4 v3 = *((const ushort4*)(h + (size_t)s3 * HID) + lane);
    a0.x += b2f(v0.x); a0.y += b2f(v0.y); a0.z += b2f(v0.z); a0.w += b2f(v0.w);
    a1.x += b2f(v1.x); a1.y += b2f(v1.y); a1.z += b2f(v1.z); a1.w += b2f(v1.w);
    a2.x += b2f(v2.x); a2.y += b2f(v2.y); a2.z += b2f(v2.z); a2.w += b2f(v2.w);
    a3.x += b2f(v3.x); a3.y += b2f(v3.y); a3.z += b2f(v3.z); a3.w += b2f(v3.w);
  }
  for (; r < r1; r++) {
    int s0 = col[r];
    ushort4 v0 = *((const ushort4*)(h + (size_t)s0 * HID) + lane);
    a0.x += b2f(v0.x); a0.y += b2f(v0.y); a0.z += b2f(v0.z); a0.w += b2f(v0.w);
  }
  float inv = inv_cnt[node];
  ushort4 o;
  o.x = f2b((a0.x + a1.x + a2.x + a3.x) * inv);
  o.y = f2b((a0.y + a1.y + a2.y + a3.y) * inv);
  o.z = f2b((a0.z + a1.z + a2.z + a3.z) * inv);
  o.w = f2b((a0.w + a1.w + a2.w + a3.w) * inv);
  *((ushort4*)(aggr + (size_t)node * HID) + lane) = o;
}

// ------------------------------------------------------------ MFMA GEMM -----
// hpre[m][n] = sum_k cat(aggr,h)[m][k] * B[k][n],  B^T given as Wt[n][k].
// 128x128 tile, BK=32, 4 waves each 64x64, 16x16x32 bf16 MFMA.
// 16B-chunk XOR swizzle: LDS chunk-slot c holds global chunk c ^ ((row>>1)&3).
__global__ __launch_bounds__(256) void gemm_mfma(
    const u16* __restrict__ hb, const u16* __restrict__ aggr,
    const u16* __restrict__ Bt, u16* __restrict__ hpre) {
  __shared__ u16 As[128 * 32];
  __shared__ u16 Bs[128 * 32];
  int tid = threadIdx.x;
  int wid = tid >> 6, lane = tid & 63;
  int m0 = blockIdx.x * 128;
  int n0 = blockIdx.y * 128;
  int q = lane >> 4, c = lane & 15;
  int wm = (wid >> 1) * 64, wn = (wid & 1) * 64;

  f32x4 zero = {0.f, 0.f, 0.f, 0.f};
  f32x4 acc[4][4];
#pragma unroll
  for (int mi = 0; mi < 4; mi++)
#pragma unroll
    for (int ni = 0; ni < 4; ni++) acc[mi][ni] = zero;

  // staging geometry (loop-invariant)
  int srow0 = wid * 32 + (lane >> 2);       // t=0 row
  int cg0 = (lane & 3) ^ ((srow0 >> 1) & 3);
  int srow1 = srow0 + 16;                    // t=1 row
  int cg1 = (lane & 3) ^ ((srow1 >> 1) & 3);

  // frag-read LDS offsets (elements), loop-invariant
  int aoff[4], boff[4];
#pragma unroll
  for (int mi = 0; mi < 4; mi++) {
    int row = wm + mi * 16 + c;
    aoff[mi] = row * 32 + ((q ^ ((row >> 1) & 3)) << 3);
  }
#pragma unroll
  for (int ni = 0; ni < 4; ni++) {
    int row = wn + ni * 16 + c;
    boff[ni] = row * 32 + ((q ^ ((row >> 1) & 3)) << 3);
  }

  for (int k0 = 0; k0 < 512; k0 += 32) {
    const u16* Asrc = (k0 < 256) ? aggr : hb;
    int ksrc = k0 & 255;
    gload16(Asrc + ((size_t)(m0 + srow0) * HID + ksrc + cg0 * 8), &As[(wid * 32) * 32]);
    gload16(Asrc + ((size_t)(m0 + srow1) * HID + ksrc + cg1 * 8), &As[(wid * 32 + 16) * 32]);
    gload16(Bt + ((size_t)(n0 + srow0) * 512 + k0 + cg0 * 8), &Bs[(wid * 32) * 32]);
    gload16(Bt + ((size_t)(n0 + srow1) * 512 + k0 + cg1 * 8), &Bs[(wid * 32 + 16) * 32]);
    __syncthreads();
    bf16x8 af[4], bfr[4];
#pragma unroll
    for (int mi = 0; mi < 4; mi++) af[mi] = *(const bf16x8*)&As[aoff[mi]];
#pragma unroll
    for (int ni = 0; ni < 4; ni++) bfr[ni] = *(const bf16x8*)&Bs[boff[ni]];
#pragma unroll
    for (int mi = 0; mi < 4; mi++)
#pragma unroll
      for (int ni = 0; ni < 4; ni++)
        acc[mi][ni] = __builtin_amdgcn_mfma_f32_16x16x32_bf16(af[mi], bfr[ni],
                                                              acc[mi][ni], 0, 0, 0);
    __syncthreads();
  }

  // epilogue: C/D layout col=lane&15, row=(lane>>4)*4+reg
#pragma unroll
  for (int mi = 0; mi < 4; mi++) {
#pragma unroll
    for (int r = 0; r < 4; r++) {
      int gm = m0 + wm + mi * 16 + q * 4 + r;
      if (gm < N_NODES) {
#pragma unroll
        for (int ni = 0; ni < 4; ni++) {
          int gn = n0 + wn + ni * 16 + c;
          hpre[(size_t)gm * HID + gn] = f2b(acc[mi][ni][r]);
        }
      }
    }
  }
}

// ------------------------------------------------------------ batchnorm -----
#define BN_ROWS 500
__global__ __launch_bounds__(256) void bn_reduce_bf16(const u16* __restrict__ h,
                                                      float* __restrict__ sums) {
  int f = threadIdx.x;
  int r0 = blockIdx.x * BN_ROWS;
  int r1 = r0 + BN_ROWS;
  float s = 0.f, s2 = 0.f;
  for (int r = r0; r < r1; r++) {
    float v = b2f(h[(size_t)r * HID + f]);
    s += v;
    s2 += v * v;
  }
  atomicAdd(&sums[f], s);
  atomicAdd(&sums[HID + f], s2);
}

__global__ void bn_finalize(const float* __restrict__ sums,
                            const float* __restrict__ gamma,
                            const float* __restrict__ beta,
                            float* __restrict__ ss) {
  int f = threadIdx.x;
  const float invN = 1.0f / (float)N_NODES;
  float mu = sums[f] * invN;
  float ex2 = sums[HID + f] * invN;
  float var = fmaxf(ex2 - mu * mu, 0.f);
  float sc = gamma[f] * rsqrtf(var + 1e-5f);
  ss[f] = sc;
  ss[HID + f] = beta[f] - mu * sc;
}

__global__ __launch_bounds__(256) void bn_apply_bf16(const uint4* __restrict__ hpre,
                                                     const float* __restrict__ ss,
                                                     uint4* __restrict__ hout) {
  int idx0 = blockIdx.x * blockDim.x + threadIdx.x;
  int cb = (idx0 & 31) * 8;  // column base (row = 32 uint4)
  float sc[8], sh[8];
#pragma unroll
  for (int j = 0; j < 8; j++) { sc[j] = ss[cb + j]; sh[j] = ss[HID + cb + j]; }
  const int total = N_NODES * 32;
  const int step = gridDim.x * blockDim.x;  // 524288, multiple of 32
  for (int i = idx0; i < total; i += step) {
    uint4 v = hpre[i];
    unsigned vv[4] = {v.x, v.y, v.z, v.w};
    unsigned o[4];
#pragma unroll
    for (int j = 0; j < 4; j++) {
      float lo = __uint_as_float(vv[j] << 16);
      float hi = __uint_as_float(vv[j] & 0xFFFF0000u);
      lo = fmaxf(fmaf(lo, sc[2 * j], sh[2 * j]), 0.f);
      hi = fmaxf(fmaf(hi, sc[2 * j + 1], sh[2 * j + 1]), 0.f);
      o[j] = (unsigned)f2b(lo) | ((unsigned)f2b(hi) << 16);
    }
    uint4 ov = {o[0], o[1], o[2], o[3]};
    hout[i] = ov;
  }
}

// ----------------------------------------------------------------- pool -----
#define ROWS_PER_BLOCK 512
__global__ __launch_bounds__(256) void pool_kernel(const u16* __restrict__ h,
                                                   const int* __restrict__ batch,
                                                   float* __restrict__ gacc,
                                                   float* __restrict__ gcnt) {
  int f = threadIdx.x;
  int r0 = blockIdx.x * ROWS_PER_BLOCK;
  if (r0 >= N_NODES) return;
  int r1 = min(r0 + ROWS_PER_BLOCK, N_NODES);
  int cur = batch[r0];
  float acc = 0.f, count = 0.f;
  for (int r = r0; r < r1; r++) {
    int b = batch[r];
    if (b != cur) {
      atomicAdd(&gacc[(size_t)cur * HID + f], acc);
      if (f == 0) atomicAdd(&gcnt[cur], count);
      acc = 0.f;
      count = 0.f;
      cur = b;
    }
    acc += b2f(h[(size_t)r * HID + f]);
    count += 1.f;
  }
  atomicAdd(&gacc[(size_t)cur * HID + f], acc);
  if (f == 0) atomicAdd(&gcnt[cur], count);
}

// ------------------------------------------------------------------ MLP -----
__global__ __launch_bounds__(256) void mlp_kernel(
    const float* __restrict__ gacc, const float* __restrict__ gcnt,
    const float* __restrict__ W1, const float* __restrict__ b1,
    const float* __restrict__ W2, const float* __restrict__ b2,
    float* __restrict__ out) {
  __shared__ float gs[HID];
  __shared__ float ts[HID];
  __shared__ float red[PROJ];
  int g = blockIdx.x;
  int t = threadIdx.x;
  float inv = 1.0f / fmaxf(gcnt[g], 1.0f);
  gs[t] = gacc[(size_t)g * HID + t] * inv;
  __syncthreads();
  float s = b1[t];
  for (int k = 0; k < HID; k++) s = fmaf(gs[k], W1[(size_t)k * HID + t], s);
  ts[t] = fmaxf(s, 0.f);
  __syncthreads();
  float z = 0.f;
  if (t < PROJ) {
    z = b2[t];
    for (int k = 0; k < HID; k++) z = fmaf(ts[k], W2[(size_t)k * PROJ + t], z);
    red[t] = z * z;
  }
  __syncthreads();
  for (int off = PROJ / 2; off > 0; off >>= 1) {
    if (t < off) red[t] += red[t + off];
    __syncthreads();
  }
  float norm = fmaxf(sqrtf(red[0]), 1e-12f);
  if (t < PROJ) out[(size_t)g * PROJ + t] = z / norm;
}

// --------------------------------------------------------------- launch -----
extern "C" void kernel_launch(void* const* d_in, const int* in_sizes, int n_in,
                              void* d_out, int out_size, void* d_ws, size_t ws_size,
                              hipStream_t stream) {
  const float* x = (const float*)d_in[0];
  const int* ei = (const int*)d_in[1];
  const int* src = ei;
  const int* dst = ei + N_EDGES;
  const int* batch = (const int*)d_in[2];
  const float* Wl = (const float*)d_in[3];
  // d_in[4] = bl: per-column bias is exactly cancelled by BatchNorm -> unused
  const float* Wr = (const float*)d_in[5];
  const float* gamma = (const float*)d_in[6];
  const float* beta = (const float*)d_in[7];
  const float* W1 = (const float*)d_in[8];
  const float* b1 = (const float*)d_in[9];
  const float* W2 = (const float*)d_in[10];
  const float* b2 = (const float*)d_in[11];
  float* out = (float*)d_out;

  char* p = (char*)d_ws;
  const size_t HB = (size_t)M_PAD * HID * sizeof(u16);  // 51.25 MB
  u16* hb0 = (u16*)p;    p += HB;
  u16* hb1 = (u16*)p;    p += HB;
  u16* aggr = (u16*)p;   p += HB;
  u16* hpre = (u16*)p;   p += HB;
  u16* Wt = (u16*)p;     p += (size_t)NLAYERS * 512 * HID * sizeof(u16);  // 1 MB
  int* col = (int*)p;    p += (size_t)N_EDGES * sizeof(int);              // 6.4 MB
  int* row_ptr = (int*)p; p += 400016;
  float* inv_cnt = (float*)p; p += (size_t)N_NODES * sizeof(float);
  float* sums = (float*)p;    p += 512 * sizeof(float);
  float* ss = (float*)p;      p += 512 * sizeof(float);
  float* gacc = (float*)p;    p += (size_t)N_GRAPHS * HID * sizeof(float);
  float* gcnt = (float*)p;    p += N_GRAPHS * sizeof(float);

  // transient CSR-build arrays overlaid into hpre (first written in layer-0 gemm)
  int* counts = (int*)hpre;
  int* fill = counts + N_NODES;

  // ---- build CSR (once; edge_index is layer-invariant) ----
  hipMemsetAsync(counts, 0, 2 * (size_t)N_NODES * sizeof(int), stream);
  count_kernel<<<(N_EDGES + 255) / 256, 256, 0, stream>>>(dst, counts);
  inv_kernel<<<(N_NODES + 255) / 256, 256, 0, stream>>>(counts, inv_cnt);
  scan_kernel<<<1, 256, 0, stream>>>(counts, row_ptr);
  fill_kernel<<<(N_EDGES + 255) / 256, 256, 0, stream>>>(src, dst, row_ptr, fill, col);

  // ---- one-time converts ----
  convert_x<<<N_NODES / 4, 256, 0, stream>>>((const float4*)x, (ushort4*)hb0);
  convert_w<<<(NLAYERS * 512 * HID) / 256, 256, 0, stream>>>(Wl, Wr, Wt);

  u16* hcur = hb0;
  u16* hnext = hb1;
  for (int l = 0; l < NLAYERS; l++) {
    aggregate_bf16<<<N_NODES / 4, 256, 0, stream>>>(hcur, row_ptr, col, inv_cnt, aggr);
    gemm_mfma<<<dim3(M_PAD / 128, HID / 128), 256, 0, stream>>>(
        hcur, aggr, Wt + (size_t)l * 512 * HID, hpre);
    hipMemsetAsync(sums, 0, 512 * sizeof(float), stream);
    bn_reduce_bf16<<<N_NODES / BN_ROWS, 256, 0, stream>>>(hpre, sums);
    bn_finalize<<<1, 256, 0, stream>>>(sums, gamma + (size_t)l * HID,
                                       beta + (size_t)l * HID, ss);
    bn_apply_bf16<<<2048, 256, 0, stream>>>((const uint4*)hpre, ss, (uint4*)hnext);
    u16* t = hcur; hcur = hnext; hnext = t;
  }

  hipMemsetAsync(gacc, 0, (size_t)(N_GRAPHS * HID + N_GRAPHS) * sizeof(float), stream);
  pool_kernel<<<(N_NODES + ROWS_PER_BLOCK - 1) / ROWS_PER_BLOCK, 256, 0, stream>>>(
      hcur, batch, gacc, gcnt);
  mlp_kernel<<<N_GRAPHS, 256, 0, stream>>>(gacc, gcnt, W1, b1, W2, b2, out);
}

// Round 4
// 1325.856 us; speedup vs baseline: 6.4088x; 1.3057x over previous
//
#include <hip/hip_runtime.h>

#define N_NODES 100000
#define M_PAD   100096   // 782 * 128
#define N_EDGES 1600000
#define N_GRAPHS 64
#define HID 256
#define PROJ 128
#define NLAYERS 4

typedef unsigned short u16;
typedef __attribute__((ext_vector_type(8))) short bf16x8;
typedef __attribute__((ext_vector_type(4))) float f32x4;

__device__ __forceinline__ float b2f(u16 u) {
  return __uint_as_float(((unsigned)u) << 16);
}
__device__ __forceinline__ float b2f_lo(unsigned u) {
  return __uint_as_float(u << 16);
}
__device__ __forceinline__ float b2f_hi(unsigned u) {
  return __uint_as_float(u & 0xFFFF0000u);
}
__device__ __forceinline__ u16 f2b(float f) {
  unsigned u = __float_as_uint(f);
  u = (u + 0x7FFF + ((u >> 16) & 1)) >> 16;  // round-to-nearest-even
  return (u16)u;
}
__device__ __forceinline__ void gload16(const void* g, void* l) {
  __builtin_amdgcn_global_load_lds((const __attribute__((address_space(1))) void*)g,
                                   (__attribute__((address_space(3))) void*)l, 16, 0, 0);
}

// ---------------------------------------------------------------- CSR -------
__global__ void count_kernel(const int* __restrict__ dst, int* __restrict__ cnt) {
  int e = blockIdx.x * blockDim.x + threadIdx.x;
  if (e < N_EDGES) atomicAdd(&cnt[dst[e]], 1);
}

__global__ void inv_kernel(const int* __restrict__ cnt, float* __restrict__ inv) {
  int n = blockIdx.x * blockDim.x + threadIdx.x;
  if (n < N_NODES) inv[n] = 1.0f / fmaxf((float)cnt[n], 1.0f);
}

// ---- 3-phase multi-block exclusive scan (replaces 422us single-block scan) --
#define SCAN_BLK 1024
#define N_SCAN_BLOCKS ((N_NODES + SCAN_BLK - 1) / SCAN_BLK)  // 98

__global__ __launch_bounds__(256) void scan_partial(const int* __restrict__ cnt,
                                                    int* __restrict__ bsum) {
  __shared__ int red[256];
  int t = threadIdx.x;
  int base = blockIdx.x * SCAN_BLK + t * 4;
  int s = 0;
#pragma unroll
  for (int j = 0; j < 4; j++) {
    int i = base + j;
    if (i < N_NODES) s += cnt[i];
  }
  red[t] = s;
  __syncthreads();
  for (int off = 128; off > 0; off >>= 1) {
    if (t < off) red[t] += red[t + off];
    __syncthreads();
  }
  if (t == 0) bsum[blockIdx.x] = red[0];
}

__global__ __launch_bounds__(128) void scan_bsums(const int* __restrict__ bsum,
                                                  int* __restrict__ boff) {
  __shared__ int tile[128];
  int t = threadIdx.x;
  int v = (t < N_SCAN_BLOCKS) ? bsum[t] : 0;
  tile[t] = v;
  __syncthreads();
#pragma unroll
  for (int off = 1; off < 128; off <<= 1) {
    int add = (t >= off) ? tile[t - off] : 0;
    __syncthreads();
    tile[t] += add;
    __syncthreads();
  }
  if (t < N_SCAN_BLOCKS) boff[t] = tile[t] - v;  // exclusive
}

__global__ __launch_bounds__(256) void scan_final(const int* __restrict__ cnt,
                                                  const int* __restrict__ boff,
                                                  int* __restrict__ row_ptr) {
  __shared__ int tsum[256];
  int t = threadIdx.x;
  int base = blockIdx.x * SCAN_BLK + t * 4;
  int v[4];
  int s = 0;
#pragma unroll
  for (int j = 0; j < 4; j++) {
    int i = base + j;
    v[j] = (i < N_NODES) ? cnt[i] : 0;
    s += v[j];
  }
  tsum[t] = s;
  __syncthreads();
#pragma unroll
  for (int off = 1; off < 256; off <<= 1) {
    int add = (t >= off) ? tsum[t - off] : 0;
    __syncthreads();
    tsum[t] += add;
    __syncthreads();
  }
  int excl = tsum[t] - s + boff[blockIdx.x];
#pragma unroll
  for (int j = 0; j < 4; j++) {
    int i = base + j;
    if (i < N_NODES) {
      row_ptr[i] = excl;
      excl += v[j];
    }
  }
  if (blockIdx.x == 0 && t == 0) row_ptr[N_NODES] = N_EDGES;
}

__global__ void fill_kernel(const int* __restrict__ src, const int* __restrict__ dst,
                            const int* __restrict__ row_ptr, int* __restrict__ fill,
                            int* __restrict__ col) {
  int e = blockIdx.x * blockDim.x + threadIdx.x;
  if (e < N_EDGES) {
    int d = dst[e];
    int pos = row_ptr[d] + atomicAdd(&fill[d], 1);
    col[pos] = src[e];
  }
}

// ------------------------------------------------------------ converts ------
__global__ __launch_bounds__(256) void convert_x(const float4* __restrict__ x,
                                                 ushort4* __restrict__ hb) {
  int i = blockIdx.x * blockDim.x + threadIdx.x;  // exactly N_NODES*64 threads
  float4 v = x[i];
  ushort4 o;
  o.x = f2b(v.x); o.y = f2b(v.y); o.z = f2b(v.z); o.w = f2b(v.w);
  hb[i] = o;
}

// Wt[l][n][k] bf16, k<256 -> Wl[l][k][n], k>=256 -> Wr[l][k-256][n]
__global__ __launch_bounds__(256) void convert_w(const float* __restrict__ Wl,
                                                 const float* __restrict__ Wr,
                                                 u16* __restrict__ Wt) {
  int idx = blockIdx.x * blockDim.x + threadIdx.x;  // 4*256*512 threads
  int l = idx >> 17;
  int r = idx & ((1 << 17) - 1);
  int n = r >> 9;
  int k = r & 511;
  float v = (k < 256) ? Wl[(size_t)l * 65536 + k * 256 + n]
                      : Wr[(size_t)l * 65536 + (k - 256) * 256 + n];
  Wt[idx] = f2b(v);
}

// ----------------------------------------------------------- aggregation ----
// one wave per node; two 32-lane halves process alternating edges with 16B loads;
// lane l32 holds features [l32*8, l32*8+8); cross-half merge via shfl_xor(32).
__global__ __launch_bounds__(256) void aggregate_bf16(
    const u16* __restrict__ h, const int* __restrict__ row_ptr,
    const int* __restrict__ col, const float* __restrict__ inv_cnt,
    u16* __restrict__ aggr) {
  int node = blockIdx.x * 4 + (threadIdx.x >> 6);
  int lane = threadIdx.x & 63;
  int half = lane >> 5, l32 = lane & 31;
  int r0 = row_ptr[node], r1 = row_ptr[node + 1];
  float a[8] = {0.f, 0.f, 0.f, 0.f, 0.f, 0.f, 0.f, 0.f};
  int e = r0 + half;
  for (; e + 2 < r1; e += 4) {
    int s0 = col[e], s1 = col[e + 2];
    uint4 v0 = *((const uint4*)(h + (size_t)s0 * HID) + l32);
    uint4 v1 = *((const uint4*)(h + (size_t)s1 * HID) + l32);
    a[0] += b2f_lo(v0.x); a[1] += b2f_hi(v0.x);
    a[2] += b2f_lo(v0.y); a[3] += b2f_hi(v0.y);
    a[4] += b2f_lo(v0.z); a[5] += b2f_hi(v0.z);
    a[6] += b2f_lo(v0.w); a[7] += b2f_hi(v0.w);
    a[0] += b2f_lo(v1.x); a[1] += b2f_hi(v1.x);
    a[2] += b2f_lo(v1.y); a[3] += b2f_hi(v1.y);
    a[4] += b2f_lo(v1.z); a[5] += b2f_hi(v1.z);
    a[6] += b2f_lo(v1.w); a[7] += b2f_hi(v1.w);
  }
  for (; e < r1; e += 2) {
    int s0 = col[e];
    uint4 v0 = *((const uint4*)(h + (size_t)s0 * HID) + l32);
    a[0] += b2f_lo(v0.x); a[1] += b2f_hi(v0.x);
    a[2] += b2f_lo(v0.y); a[3] += b2f_hi(v0.y);
    a[4] += b2f_lo(v0.z); a[5] += b2f_hi(v0.z);
    a[6] += b2f_lo(v0.w); a[7] += b2f_hi(v0.w);
  }
#pragma unroll
  for (int j = 0; j < 8; j++) a[j] += __shfl_xor(a[j], 32, 64);
  if (half == 0) {
    float inv = inv_cnt[node];
    uint4 o;
    o.x = (unsigned)f2b(a[0] * inv) | ((unsigned)f2b(a[1] * inv) << 16);
    o.y = (unsigned)f2b(a[2] * inv) | ((unsigned)f2b(a[3] * inv) << 16);
    o.z = (unsigned)f2b(a[4] * inv) | ((unsigned)f2b(a[5] * inv) << 16);
    o.w = (unsigned)f2b(a[6] * inv) | ((unsigned)f2b(a[7] * inv) << 16);
    *((uint4*)(aggr + (size_t)node * HID) + l32) = o;
  }
}

// ------------------------------------------------------------ MFMA GEMM -----
// hpre[m][n] = sum_k cat(aggr,h)[m][k] * B[k][n],  B^T given as Wt[n][k].
// 128x128 tile, BK=32, 4 waves each 64x64, 16x16x32 bf16 MFMA.
// 16B-chunk XOR swizzle: LDS chunk-slot c holds global chunk c ^ ((row>>1)&3).
__global__ __launch_bounds__(256) void gemm_mfma(
    const u16* __restrict__ hb, const u16* __restrict__ aggr,
    const u16* __restrict__ Bt, u16* __restrict__ hpre) {
  __shared__ u16 As[128 * 32];
  __shared__ u16 Bs[128 * 32];
  int tid = threadIdx.x;
  int wid = tid >> 6, lane = tid & 63;
  int m0 = blockIdx.x * 128;
  int n0 = blockIdx.y * 128;
  int q = lane >> 4, c = lane & 15;
  int wm = (wid >> 1) * 64, wn = (wid & 1) * 64;

  f32x4 zero = {0.f, 0.f, 0.f, 0.f};
  f32x4 acc[4][4];
#pragma unroll
  for (int mi = 0; mi < 4; mi++)
#pragma unroll
    for (int ni = 0; ni < 4; ni++) acc[mi][ni] = zero;

  // staging geometry (loop-invariant)
  int srow0 = wid * 32 + (lane >> 2);       // t=0 row
  int cg0 = (lane & 3) ^ ((srow0 >> 1) & 3);
  int srow1 = srow0 + 16;                    // t=1 row
  int cg1 = (lane & 3) ^ ((srow1 >> 1) & 3);

  // frag-read LDS offsets (elements), loop-invariant
  int aoff[4], boff[4];
#pragma unroll
  for (int mi = 0; mi < 4; mi++) {
    int row = wm + mi * 16 + c;
    aoff[mi] = row * 32 + ((q ^ ((row >> 1) & 3)) << 3);
  }
#pragma unroll
  for (int ni = 0; ni < 4; ni++) {
    int row = wn + ni * 16 + c;
    boff[ni] = row * 32 + ((q ^ ((row >> 1) & 3)) << 3);
  }

  for (int k0 = 0; k0 < 512; k0 += 32) {
    const u16* Asrc = (k0 < 256) ? aggr : hb;
    int ksrc = k0 & 255;
    gload16(Asrc + ((size_t)(m0 + srow0) * HID + ksrc + cg0 * 8), &As[(wid * 32) * 32]);
    gload16(Asrc + ((size_t)(m0 + srow1) * HID + ksrc + cg1 * 8), &As[(wid * 32 + 16) * 32]);
    gload16(Bt + ((size_t)(n0 + srow0) * 512 + k0 + cg0 * 8), &Bs[(wid * 32) * 32]);
    gload16(Bt + ((size_t)(n0 + srow1) * 512 + k0 + cg1 * 8), &Bs[(wid * 32 + 16) * 32]);
    __syncthreads();
    bf16x8 af[4], bfr[4];
#pragma unroll
    for (int mi = 0; mi < 4; mi++) af[mi] = *(const bf16x8*)&As[aoff[mi]];
#pragma unroll
    for (int ni = 0; ni < 4; ni++) bfr[ni] = *(const bf16x8*)&Bs[boff[ni]];
#pragma unroll
    for (int mi = 0; mi < 4; mi++)
#pragma unroll
      for (int ni = 0; ni < 4; ni++)
        acc[mi][ni] = __builtin_amdgcn_mfma_f32_16x16x32_bf16(af[mi], bfr[ni],
                                                              acc[mi][ni], 0, 0, 0);
    __syncthreads();
  }

  // epilogue: C/D layout col=lane&15, row=(lane>>4)*4+reg
#pragma unroll
  for (int mi = 0; mi < 4; mi++) {
#pragma unroll
    for (int r = 0; r < 4; r++) {
      int gm = m0 + wm + mi * 16 + q * 4 + r;
      if (gm < N_NODES) {
#pragma unroll
        for (int ni = 0; ni < 4; ni++) {
          int gn = n0 + wn + ni * 16 + c;
          hpre[(size_t)gm * HID + gn] = f2b(acc[mi][ni][r]);
        }
      }
    }
  }
}

// ------------------------------------------------------------ batchnorm -----
#define BN_ROWS 500
__global__ __launch_bounds__(256) void bn_reduce_bf16(const u16* __restrict__ h,
                                                      float* __restrict__ sums) {
  int f = threadIdx.x;
  int r0 = blockIdx.x * BN_ROWS;
  int r1 = r0 + BN_ROWS;
  float s = 0.f, s2 = 0.f;
  for (int r = r0; r < r1; r++) {
    float v = b2f(h[(size_t)r * HID + f]);
    s += v;
    s2 += v * v;
  }
  atomicAdd(&sums[f], s);
  atomicAdd(&sums[HID + f], s2);
}

__global__ void bn_finalize(const float* __restrict__ sums,
                            const float* __restrict__ gamma,
                            const float* __restrict__ beta,
                            float* __restrict__ ss) {
  int f = threadIdx.x;
  const float invN = 1.0f / (float)N_NODES;
  float mu = sums[f] * invN;
  float ex2 = sums[HID + f] * invN;
  float var = fmaxf(ex2 - mu * mu, 0.f);
  float sc = gamma[f] * rsqrtf(var + 1e-5f);
  ss[f] = sc;
  ss[HID + f] = beta[f] - mu * sc;
}

__global__ __launch_bounds__(256) void bn_apply_bf16(const uint4* __restrict__ hpre,
                                                     const float* __restrict__ ss,
                                                     uint4* __restrict__ hout) {
  int idx0 = blockIdx.x * blockDim.x + threadIdx.x;
  int cb = (idx0 & 31) * 8;  // column base (row = 32 uint4)
  float sc[8], sh[8];
#pragma unroll
  for (int j = 0; j < 8; j++) { sc[j] = ss[cb + j]; sh[j] = ss[HID + cb + j]; }
  const int total = N_NODES * 32;
  const int step = gridDim.x * blockDim.x;  // 524288, multiple of 32
  for (int i = idx0; i < total; i += step) {
    uint4 v = hpre[i];
    unsigned vv[4] = {v.x, v.y, v.z, v.w};
    unsigned o[4];
#pragma unroll
    for (int j = 0; j < 4; j++) {
      float lo = b2f_lo(vv[j]);
      float hi = b2f_hi(vv[j]);
      lo = fmaxf(fmaf(lo, sc[2 * j], sh[2 * j]), 0.f);
      hi = fmaxf(fmaf(hi, sc[2 * j + 1], sh[2 * j + 1]), 0.f);
      o[j] = (unsigned)f2b(lo) | ((unsigned)f2b(hi) << 16);
    }
    uint4 ov = {o[0], o[1], o[2], o[3]};
    hout[i] = ov;
  }
}

// ----------------------------------------------------------------- pool -----
#define ROWS_PER_BLOCK 512
__global__ __launch_bounds__(256) void pool_kernel(const u16* __restrict__ h,
                                                   const int* __restrict__ batch,
                                                   float* __restrict__ gacc,
                                                   float* __restrict__ gcnt) {
  int f = threadIdx.x;
  int r0 = blockIdx.x * ROWS_PER_BLOCK;
  if (r0 >= N_NODES) return;
  int r1 = min(r0 + ROWS_PER_BLOCK, N_NODES);
  int cur = batch[r0];
  float acc = 0.f, count = 0.f;
  for (int r = r0; r < r1; r++) {
    int b = batch[r];
    if (b != cur) {
      atomicAdd(&gacc[(size_t)cur * HID + f], acc);
      if (f == 0) atomicAdd(&gcnt[cur], count);
      acc = 0.f;
      count = 0.f;
      cur = b;
    }
    acc += b2f(h[(size_t)r * HID + f]);
    count += 1.f;
  }
  atomicAdd(&gacc[(size_t)cur * HID + f], acc);
  if (f == 0) atomicAdd(&gcnt[cur], count);
}

// ------------------------------------------------------------------ MLP -----
__global__ __launch_bounds__(256) void mlp_kernel(
    const float* __restrict__ gacc, const float* __restrict__ gcnt,
    const float* __restrict__ W1, const float* __restrict__ b1,
    const float* __restrict__ W2, const float* __restrict__ b2,
    float* __restrict__ out) {
  __shared__ float gs[HID];
  __shared__ float ts[HID];
  __shared__ float red[PROJ];
  int g = blockIdx.x;
  int t = threadIdx.x;
  float inv = 1.0f / fmaxf(gcnt[g], 1.0f);
  gs[t] = gacc[(size_t)g * HID + t] * inv;
  __syncthreads();
  float s = b1[t];
  for (int k = 0; k < HID; k++) s = fmaf(gs[k], W1[(size_t)k * HID + t], s);
  ts[t] = fmaxf(s, 0.f);
  __syncthreads();
  float z = 0.f;
  if (t < PROJ) {
    z = b2[t];
    for (int k = 0; k < HID; k++) z = fmaf(ts[k], W2[(size_t)k * PROJ + t], z);
    red[t] = z * z;
  }
  __syncthreads();
  for (int off = PROJ / 2; off > 0; off >>= 1) {
    if (t < off) red[t] += red[t + off];
    __syncthreads();
  }
  float norm = fmaxf(sqrtf(red[0]), 1e-12f);
  if (t < PROJ) out[(size_t)g * PROJ + t] = z / norm;
}

// --------------------------------------------------------------- launch -----
extern "C" void kernel_launch(void* const* d_in, const int* in_sizes, int n_in,
                              void* d_out, int out_size, void* d_ws, size_t ws_size,
                              hipStream_t stream) {
  const float* x = (const float*)d_in[0];
  const int* ei = (const int*)d_in[1];
  const int* src = ei;
  const int* dst = ei + N_EDGES;
  const int* batch = (const int*)d_in[2];
  const float* Wl = (const float*)d_in[3];
  // d_in[4] = bl: per-column bias is exactly cancelled by BatchNorm -> unused
  const float* Wr = (const float*)d_in[5];
  const float* gamma = (const float*)d_in[6];
  const float* beta = (const float*)d_in[7];
  const float* W1 = (const float*)d_in[8];
  const float* b1 = (const float*)d_in[9];
  const float* W2 = (const float*)d_in[10];
  const float* b2 = (const float*)d_in[11];
  float* out = (float*)d_out;

  char* p = (char*)d_ws;
  const size_t HB = (size_t)M_PAD * HID * sizeof(u16);  // 51.25 MB
  u16* hb0 = (u16*)p;    p += HB;
  u16* hb1 = (u16*)p;    p += HB;
  u16* aggr = (u16*)p;   p += HB;
  u16* hpre = (u16*)p;   p += HB;
  u16* Wt = (u16*)p;     p += (size_t)NLAYERS * 512 * HID * sizeof(u16);  // 1 MB
  int* col = (int*)p;    p += (size_t)N_EDGES * sizeof(int);              // 6.4 MB
  int* row_ptr = (int*)p; p += 400016;
  float* inv_cnt = (float*)p; p += (size_t)N_NODES * sizeof(float);
  float* sums = (float*)p;    p += 512 * sizeof(float);
  float* ss = (float*)p;      p += 512 * sizeof(float);
  float* gacc = (float*)p;    p += (size_t)N_GRAPHS * HID * sizeof(float);
  float* gcnt = (float*)p;    p += N_GRAPHS * sizeof(float);
  int* bsum = (int*)p;        p += 128 * sizeof(int);
  int* boff = (int*)p;        p += 128 * sizeof(int);

  // transient CSR-build arrays overlaid into hpre (first written in layer-0 gemm)
  int* counts = (int*)hpre;
  int* fill = counts + N_NODES;

  // ---- build CSR (once; edge_index is layer-invariant) ----
  hipMemsetAsync(counts, 0, 2 * (size_t)N_NODES * sizeof(int), stream);
  count_kernel<<<(N_EDGES + 255) / 256, 256, 0, stream>>>(dst, counts);
  inv_kernel<<<(N_NODES + 255) / 256, 256, 0, stream>>>(counts, inv_cnt);
  scan_partial<<<N_SCAN_BLOCKS, 256, 0, stream>>>(counts, bsum);
  scan_bsums<<<1, 128, 0, stream>>>(bsum, boff);
  scan_final<<<N_SCAN_BLOCKS, 256, 0, stream>>>(counts, boff, row_ptr);
  fill_kernel<<<(N_EDGES + 255) / 256, 256, 0, stream>>>(src, dst, row_ptr, fill, col);

  // ---- one-time converts ----
  convert_x<<<N_NODES / 4, 256, 0, stream>>>((const float4*)x, (ushort4*)hb0);
  convert_w<<<(NLAYERS * 512 * HID) / 256, 256, 0, stream>>>(Wl, Wr, Wt);

  u16* hcur = hb0;
  u16* hnext = hb1;
  for (int l = 0; l < NLAYERS; l++) {
    aggregate_bf16<<<N_NODES / 4, 256, 0, stream>>>(hcur, row_ptr, col, inv_cnt, aggr);
    gemm_mfma<<<dim3(M_PAD / 128, HID / 128), 256, 0, stream>>>(
        hcur, aggr, Wt + (size_t)l * 512 * HID, hpre);
    hipMemsetAsync(sums, 0, 512 * sizeof(float), stream);
    bn_reduce_bf16<<<N_NODES / BN_ROWS, 256, 0, stream>>>(hpre, sums);
    bn_finalize<<<1, 256, 0, stream>>>(sums, gamma + (size_t)l * HID,
                                       beta + (size_t)l * HID, ss);
    bn_apply_bf16<<<2048, 256, 0, stream>>>((const uint4*)hpre, ss, (uint4*)hnext);
    u16* t = hcur; hcur = hnext; hnext = t;
  }

  hipMemsetAsync(gacc, 0, (size_t)(N_GRAPHS * HID + N_GRAPHS) * sizeof(float), stream);
  pool_kernel<<<(N_NODES + ROWS_PER_BLOCK - 1) / ROWS_PER_BLOCK, 256, 0, stream>>>(
      hcur, batch, gacc, gcnt);
  mlp_kernel<<<N_GRAPHS, 256, 0, stream>>>(gacc, gcnt, W1, b1, W2, b2, out);
}